// Round 2
// baseline (471.473 us; speedup 1.0000x reference)
//
#include <hip/hip_runtime.h>
#include <cstdint>

typedef unsigned int u32;
typedef unsigned short u16;
typedef _Float16 h2 __attribute__((ext_vector_type(2)));

// ---------------- workspace byte offsets (written by vit_prep) ----------------
#define WS_W1A   0        // [3*16*49][8] f16  : W1 patch-part, i in [0,8)   (37632 B)
#define WS_W1B   37632    // [3*16*49][8] f16  : W1 patch-part, i in [8,16)  (37632 B)
#define WS_CQ    75264    // [3*16*49] f32     : pos-emb-folded bias          (9408 B)
#define WS_W2A   84672    // [3*8*49][8] f16   : W2, i in [0,8)              (18816 B)
#define WS_W2B   103488   // [3*8*49][8] f16   : W2, i in [8,16)             (18816 B)
#define WS_FC1W  122304   // [16*392] f32                                    (25088 B)
#define WS_FC1B  147392   // [16] f32
#define WS_FC2W  147456   // [10*16] f32
#define WS_FC2B  148096   // [10] f32
// total ws use: 148136 B

__device__ __forceinline__ u32 packh2(float a, float b) {
  h2 h; h.x = (_Float16)a; h.y = (_Float16)b;
  return __builtin_bit_cast(u32, h);
}
__device__ __forceinline__ float dot2u(u32 a, u32 b, float c) {
#if __has_builtin(__builtin_amdgcn_fdot2)
  return __builtin_amdgcn_fdot2(__builtin_bit_cast(h2, a), __builtin_bit_cast(h2, b), c, false);
#else
  h2 ha = __builtin_bit_cast(h2, a), hb = __builtin_bit_cast(h2, b);
  return c + (float)ha.x * (float)hb.x + (float)ha.y * (float)hb.y;
#endif
}

// ---------------- prep: fold pos_emb, repack weights (all inputs f32) ----------------
extern "C" __global__ void vit_prep(
    const float* __restrict__ pe,
    const float* __restrict__ wq1, const float* __restrict__ wk1, const float* __restrict__ wv1,
    const float* __restrict__ wq2, const float* __restrict__ wk2, const float* __restrict__ wv2,
    const float* __restrict__ fw1, const float* __restrict__ fb1,
    const float* __restrict__ fw2, const float* __restrict__ fb2,
    char* __restrict__ ws)
{
  const int t = blockIdx.x * 256 + threadIdx.x;
  _Float16* w1aH = (_Float16*)(ws + WS_W1A);
  _Float16* w1bH = (_Float16*)(ws + WS_W1B);
  float*    cq   = (float*)(ws + WS_CQ);
  _Float16* w2aH = (_Float16*)(ws + WS_W2A);
  _Float16* w2bH = (_Float16*)(ws + WS_W2B);
  float* o1w = (float*)(ws + WS_FC1W);
  float* o1b = (float*)(ws + WS_FC1B);
  float* o2w = (float*)(ws + WS_FC2W);
  float* o2b = (float*)(ws + WS_FC2B);

  if (t < 2352) {                       // W1 rows: t = (p*16+o)*49+s
    int p = t / 784, rem = t % 784;
    int o = rem / 49, s = rem % 49;
    const float* W = (p == 0 ? wq1 : (p == 1 ? wk1 : wv1)) + s*512 + o*32;
    #pragma unroll
    for (int i = 0; i < 8; ++i) w1aH[t*8 + i] = (_Float16)W[i];
    #pragma unroll
    for (int i = 0; i < 8; ++i) w1bH[t*8 + i] = (_Float16)W[8 + i];
    float acc = 0.f;
    #pragma unroll
    for (int i = 0; i < 16; ++i) acc += pe[s*16 + i] * W[16 + i];
    cq[t] = acc;
  } else if (t < 3528) {                // W2 rows: u = (p*8+o)*49+s
    int u = t - 2352;
    int p = u / 392, rem = u % 392;
    int o = rem / 49, s = rem % 49;
    const float* W = (p == 0 ? wq2 : (p == 1 ? wk2 : wv2)) + s*128 + o*16;
    #pragma unroll
    for (int i = 0; i < 8; ++i) w2aH[u*8 + i] = (_Float16)W[i];
    #pragma unroll
    for (int i = 0; i < 8; ++i) w2bH[u*8 + i] = (_Float16)W[8 + i];
  } else if (t < 9800) {
    int u = t - 3528; o1w[u] = fw1[u];
  } else if (t < 9816) {
    int u = t - 9800; o1b[u] = fb1[u];
  } else if (t < 9976) {
    int u = t - 9816; o2w[u] = fw2[u];
  } else if (t < 9986) {
    int u = t - 9976; o2b[u] = fb2[u];
  }
}

// ---------------- main fused kernel: wave-per-sample ----------------
// LDS: [0,122304) = weights (copied from ws), then 4 per-wave regions of 8256 B:
//   +0    : p (49x16 f16, 1568) / S1 (16x16 f32, 1024) / t3 (49x8 f32, 1568)  [time-aliased]
//   +1568 : q1 (49 rows, stride 17 f32) / later q2 (stride 9)
//   +3344 : (part of q1) / later k2 (stride 9)
//   +4912 : k1 (stride 17) / later S2(256)@5120, part(256)@5376, h(64)@5632, lg@5696
extern "C" __global__ void __launch_bounds__(256, 1)
vit_main(const float* __restrict__ x, const char* __restrict__ ws, float* __restrict__ out)
{
  __shared__ uint4 smem4[155328 / 16];
  char* smem = (char*)smem4;
  const u32 tid  = threadIdx.x;
  const u32 lane = tid & 63u;
  const u32 wv   = tid >> 6;

  { // stage all stage-1/2 weights into LDS once per block
    const uint4* src = (const uint4*)ws;
    uint4* dst = (uint4*)smem;
    for (u32 i = tid; i < (122304u / 16u); i += 256u) dst[i] = src[i];
  }
  __syncthreads();

  const uint4* w1a = (const uint4*)(smem + WS_W1A);   // row r -> 16B
  const uint4* w1b = (const uint4*)(smem + WS_W1B);
  const float* cqb = (const float*)(smem + WS_CQ);
  const uint4* w2a = (const uint4*)(smem + WS_W2A);
  const uint4* w2b = (const uint4*)(smem + WS_W2B);

  char* pw = smem + 122304 + wv * 8256;
  u32*   p2  = (u32*)pw;                 // half2[49*8]
  float* S1  = (float*)pw;               // alias
  float* t3l = (float*)pw;               // alias
  float* q1l = (float*)(pw + 1568);
  float* k1l = (float*)(pw + 4912);
  float* q2l = (float*)(pw + 1568);      // alias (q1 dead)
  float* k2l = (float*)(pw + 3344);      // alias (q1/k1 dead)
  float* S2  = (float*)(pw + 5120);
  float* prt = (float*)(pw + 5376);
  float* hbL = (float*)(pw + 5632);
  float* lg  = (float*)(pw + 5696);

  const float* f1w = (const float*)(ws + WS_FC1W);
  const float* f1b = (const float*)(ws + WS_FC1B);
  const float* f2w = (const float*)(ws + WS_FC2W);
  const float* f2b = (const float*)(ws + WS_FC2B);

  for (u32 iter = 0; iter < 16u; ++iter) {
    const u32 b = blockIdx.x * 64u + iter * 4u + wv;
    const float* xb = x + (size_t)b * 2352u;

    // ---- phase 1: grayscale + patchify -> p (f16 pairs) ----
    #pragma unroll
    for (u32 t7 = 0; t7 < 7u; ++t7) {
      u32 j = lane + t7 * 64u;           // pixel-pair index, 392 pairs
      if (j < 392u) {
        u32 R = j / 14u, C2 = j % 14u;   // col = 2*C2 (pairs never cross a patch)
        float2 rr = *(const float2*)(xb + 2u * j);
        float2 gg = *(const float2*)(xb + 784u + 2u * j);
        float2 bb = *(const float2*)(xb + 1568u + 2u * j);
        float gA = 0.299f * rr.x + 0.587f * gg.x + 0.114f * bb.x;
        float gB = 0.299f * rr.y + 0.587f * gg.y + 0.114f * bb.y;
        u32 s = (R >> 2) * 7u + (C2 >> 1);
        u32 eh = (R & 3u) * 2u + (C2 & 1u);   // e/2
        p2[s * 8u + eh] = packh2(gA, gB);
      }
    }
    __syncthreads();

    // ---- phase 2: proj1 (Q1,K1 -> LDS; V1 -> regs). Q pre-scaled by 1/7 ----
    float v1r[16];
    if (lane < 49u) {
      const u32 s = lane;
      uint4 pA = *(const uint4*)&p2[s * 8u];
      uint4 pB = *(const uint4*)&p2[s * 8u + 4u];
      #pragma unroll
      for (int o = 0; o < 16; ++o) {
        const int rq = o * 49 + (int)s;
        const int rk = (16 + o) * 49 + (int)s;
        const int rv = (32 + o) * 49 + (int)s;
        float q = cqb[rq], k = cqb[rk], v = cqb[rv];
        uint4 a = w1a[rq], c4 = w1b[rq];
        q = dot2u(pA.x, a.x, q);  q = dot2u(pA.y, a.y, q);
        q = dot2u(pA.z, a.z, q);  q = dot2u(pA.w, a.w, q);
        q = dot2u(pB.x, c4.x, q); q = dot2u(pB.y, c4.y, q);
        q = dot2u(pB.z, c4.z, q); q = dot2u(pB.w, c4.w, q);
        a = w1a[rk]; c4 = w1b[rk];
        k = dot2u(pA.x, a.x, k);  k = dot2u(pA.y, a.y, k);
        k = dot2u(pA.z, a.z, k);  k = dot2u(pA.w, a.w, k);
        k = dot2u(pB.x, c4.x, k); k = dot2u(pB.y, c4.y, k);
        k = dot2u(pB.z, c4.z, k); k = dot2u(pB.w, c4.w, k);
        a = w1a[rv]; c4 = w1b[rv];
        v = dot2u(pA.x, a.x, v);  v = dot2u(pA.y, a.y, v);
        v = dot2u(pA.z, a.z, v);  v = dot2u(pA.w, a.w, v);
        v = dot2u(pB.x, c4.x, v); v = dot2u(pB.y, c4.y, v);
        v = dot2u(pB.z, c4.z, v); v = dot2u(pB.w, c4.w, v);
        q1l[s * 17u + o] = q * (1.0f / 7.0f);
        k1l[s * 17u + o] = k;
        v1r[o] = v;
      }
    }
    __syncthreads();

    // ---- phase 3: S1[d][e] = sum_s Q[s,d]*K[s,e] (Q already scaled) ----
    {
      const u32 d = lane >> 2, eg = (lane & 3u) * 4u;
      float a0 = 0.f, a1 = 0.f, a2 = 0.f, a3 = 0.f;
      #pragma unroll 7
      for (int s2 = 0; s2 < 49; ++s2) {
        float qv = q1l[(u32)s2 * 17u + d];
        const float* kr = &k1l[(u32)s2 * 17u + eg];
        a0 = fmaf(qv, kr[0], a0);
        a1 = fmaf(qv, kr[1], a1);
        a2 = fmaf(qv, kr[2], a2);
        a3 = fmaf(qv, kr[3], a3);
      }
      float4 sv; sv.x = a0; sv.y = a1; sv.z = a2; sv.w = a3;
      *(float4*)&S1[lane * 4u] = sv;     // S1[d*16 + eg..eg+3]
    }
    __syncthreads();

    // ---- phase 4: out1 + softmax16 + proj2 (Q2,K2 -> LDS; V2 -> regs) ----
    float v2r[8];
    if (lane < 49u) {
      const u32 s = lane;
      float od[16];
      #pragma unroll
      for (int d = 0; d < 16; ++d) {
        float acc = 0.f;
        #pragma unroll
        for (int e = 0; e < 16; e += 4) {
          float4 sv = *(const float4*)&S1[d * 16 + e];   // broadcast
          acc = fmaf(sv.x, v1r[e], acc);
          acc = fmaf(sv.y, v1r[e + 1], acc);
          acc = fmaf(sv.z, v1r[e + 2], acc);
          acc = fmaf(sv.w, v1r[e + 3], acc);
        }
        od[d] = acc;
      }
      float m = od[0];
      #pragma unroll
      for (int d = 1; d < 16; ++d) m = fmaxf(m, od[d]);
      float sum = 0.f;
      #pragma unroll
      for (int d = 0; d < 16; ++d) { od[d] = __expf(od[d] - m); sum += od[d]; }
      float rs = 1.0f / sum;
      u32 th[8];
      #pragma unroll
      for (int t2 = 0; t2 < 8; ++t2) th[t2] = packh2(od[2 * t2] * rs, od[2 * t2 + 1] * rs);
      #pragma unroll
      for (int o = 0; o < 8; ++o) {
        const int rq = o * 49 + (int)s;
        const int rk = (8 + o) * 49 + (int)s;
        const int rv = (16 + o) * 49 + (int)s;
        float q = 0.f, k = 0.f, v = 0.f;
        uint4 a = w2a[rq], c4 = w2b[rq];
        q = dot2u(th[0], a.x, q);  q = dot2u(th[1], a.y, q);
        q = dot2u(th[2], a.z, q);  q = dot2u(th[3], a.w, q);
        q = dot2u(th[4], c4.x, q); q = dot2u(th[5], c4.y, q);
        q = dot2u(th[6], c4.z, q); q = dot2u(th[7], c4.w, q);
        a = w2a[rk]; c4 = w2b[rk];
        k = dot2u(th[0], a.x, k);  k = dot2u(th[1], a.y, k);
        k = dot2u(th[2], a.z, k);  k = dot2u(th[3], a.w, k);
        k = dot2u(th[4], c4.x, k); k = dot2u(th[5], c4.y, k);
        k = dot2u(th[6], c4.z, k); k = dot2u(th[7], c4.w, k);
        a = w2a[rv]; c4 = w2b[rv];
        v = dot2u(th[0], a.x, v);  v = dot2u(th[1], a.y, v);
        v = dot2u(th[2], a.z, v);  v = dot2u(th[3], a.w, v);
        v = dot2u(th[4], c4.x, v); v = dot2u(th[5], c4.y, v);
        v = dot2u(th[6], c4.z, v); v = dot2u(th[7], c4.w, v);
        q2l[s * 9u + o] = q * (1.0f / 7.0f);
        k2l[s * 9u + o] = k;
        v2r[o] = v;
      }
    }
    __syncthreads();

    // ---- phase 5: S2[d][e] ----
    {
      const u32 d = lane >> 3, e = lane & 7u;
      float acc = 0.f;
      #pragma unroll 7
      for (int s2 = 0; s2 < 49; ++s2)
        acc = fmaf(q2l[(u32)s2 * 9u + d], k2l[(u32)s2 * 9u + e], acc);
      S2[lane] = acc;
    }
    __syncthreads();

    // ---- phase 6: out2 + softmax8 -> t3 (LDS) ----
    if (lane < 49u) {
      float t3r[8];
      #pragma unroll
      for (int d = 0; d < 8; ++d) {
        float4 sa = *(const float4*)&S2[d * 8];
        float4 sb = *(const float4*)&S2[d * 8 + 4];
        float acc = sa.x * v2r[0];
        acc = fmaf(sa.y, v2r[1], acc);
        acc = fmaf(sa.z, v2r[2], acc);
        acc = fmaf(sa.w, v2r[3], acc);
        acc = fmaf(sb.x, v2r[4], acc);
        acc = fmaf(sb.y, v2r[5], acc);
        acc = fmaf(sb.z, v2r[6], acc);
        acc = fmaf(sb.w, v2r[7], acc);
        t3r[d] = acc;
      }
      float m = t3r[0];
      #pragma unroll
      for (int d = 1; d < 8; ++d) m = fmaxf(m, t3r[d]);
      float sum = 0.f;
      #pragma unroll
      for (int d = 0; d < 8; ++d) { t3r[d] = __expf(t3r[d] - m); sum += t3r[d]; }
      float rs = 1.0f / sum;
      float4 wA; wA.x = t3r[0] * rs; wA.y = t3r[1] * rs; wA.z = t3r[2] * rs; wA.w = t3r[3] * rs;
      float4 wB; wB.x = t3r[4] * rs; wB.y = t3r[5] * rs; wB.z = t3r[6] * rs; wB.w = t3r[7] * rs;
      *(float4*)&t3l[lane * 8u] = wA;
      *(float4*)&t3l[lane * 8u + 4u] = wB;
    }
    __syncthreads();

    // ---- phase 7a: fc1 partials, lane = (h, chunk) ----
    {
      const u32 hh = lane & 15u, c = lane >> 4;
      float acc = 0.f;
      #pragma unroll
      for (int jj = 0; jj < 13; ++jj) {
        int j = (int)c + jj * 4;
        if (j < 49) {
          float4 ta = *(const float4*)&t3l[j * 8];
          float4 tb = *(const float4*)&t3l[j * 8 + 4];
          const float* wr = f1w + hh * 392u + (u32)(j * 8);
          float4 wa = *(const float4*)wr;
          float4 wb = *(const float4*)(wr + 4);
          acc = fmaf(ta.x, wa.x, acc); acc = fmaf(ta.y, wa.y, acc);
          acc = fmaf(ta.z, wa.z, acc); acc = fmaf(ta.w, wa.w, acc);
          acc = fmaf(tb.x, wb.x, acc); acc = fmaf(tb.y, wb.y, acc);
          acc = fmaf(tb.z, wb.z, acc); acc = fmaf(tb.w, wb.w, acc);
        }
      }
      prt[hh * 4u + c] = acc;
    }
    __syncthreads();
    if (lane < 16u) {
      float4 pp = *(const float4*)&prt[lane * 4u];
      float hv = pp.x + pp.y + pp.z + pp.w + f1b[lane];
      hbL[lane] = fmaxf(hv, 0.f);
    }
    __syncthreads();
    if (lane < 10u) {
      const float* wr = f2w + lane * 16u;
      float acc = f2b[lane];
      float4 hv0 = *(const float4*)&hbL[0];
      float4 hv1 = *(const float4*)&hbL[4];
      float4 hv2 = *(const float4*)&hbL[8];
      float4 hv3 = *(const float4*)&hbL[12];
      float4 w0 = *(const float4*)&wr[0];
      float4 w1 = *(const float4*)&wr[4];
      float4 w2 = *(const float4*)&wr[8];
      float4 w3 = *(const float4*)&wr[12];
      acc = fmaf(hv0.x, w0.x, acc); acc = fmaf(hv0.y, w0.y, acc);
      acc = fmaf(hv0.z, w0.z, acc); acc = fmaf(hv0.w, w0.w, acc);
      acc = fmaf(hv1.x, w1.x, acc); acc = fmaf(hv1.y, w1.y, acc);
      acc = fmaf(hv1.z, w1.z, acc); acc = fmaf(hv1.w, w1.w, acc);
      acc = fmaf(hv2.x, w2.x, acc); acc = fmaf(hv2.y, w2.y, acc);
      acc = fmaf(hv2.z, w2.z, acc); acc = fmaf(hv2.w, w2.w, acc);
      acc = fmaf(hv3.x, w3.x, acc); acc = fmaf(hv3.y, w3.y, acc);
      acc = fmaf(hv3.z, w3.z, acc); acc = fmaf(hv3.w, w3.w, acc);
      lg[lane] = acc;
    }
    __syncthreads();
    if (lane < 10u) {
      float mx = lg[0];
      #pragma unroll
      for (int i2 = 1; i2 < 10; ++i2) mx = fmaxf(mx, lg[i2]);
      float sum = 0.f;
      #pragma unroll
      for (int i2 = 0; i2 < 10; ++i2) sum += __expf(lg[i2] - mx);
      float mine = __expf(lg[lane] - mx) / sum;
      out[(size_t)b * 10u + lane] = mine;
    }
    __syncthreads();   // protect per-wave LDS reuse next iteration
  }
}

extern "C" void kernel_launch(void* const* d_in, const int* in_sizes, int n_in,
                              void* d_out, int out_size, void* d_ws, size_t ws_size,
                              hipStream_t stream)
{
  const float* x   = (const float*)d_in[0];
  const float* pe  = (const float*)d_in[1];
  const float* wq1 = (const float*)d_in[2];
  const float* wk1 = (const float*)d_in[3];
  const float* wv1 = (const float*)d_in[4];
  const float* wq2 = (const float*)d_in[5];
  const float* wk2 = (const float*)d_in[6];
  const float* wv2 = (const float*)d_in[7];
  const float* f1w = (const float*)d_in[8];
  const float* f1b = (const float*)d_in[9];
  const float* f2w = (const float*)d_in[10];
  const float* f2b = (const float*)d_in[11];
  char* ws = (char*)d_ws;
  float* out = (float*)d_out;

  hipLaunchKernelGGL(vit_prep, dim3(40), dim3(256), 0, stream,
                     pe, wq1, wk1, wv1, wq2, wk2, wv2, f1w, f1b, f2w, f2b, ws);
  hipLaunchKernelGGL(vit_main, dim3(256), dim3(256), 0, stream, x, ws, out);
}

// Round 3
// 359.498 us; speedup vs baseline: 1.3115x; 1.3115x over previous
//
#include <hip/hip_runtime.h>
#include <cstdint>

typedef unsigned int u32;
typedef unsigned short u16;
typedef _Float16 h2 __attribute__((ext_vector_type(2)));

// ---------------- workspace byte offsets (written by vit_prep) ----------------
#define WS_W1A   0        // [3*16*49][8] f16 : W1 i<8   (Q rows pre-scaled 1/7)
#define WS_W1B   37632    // [3*16*49][8] f16 : W1 i 8..16
#define WS_CQ    75264    // f32[2352]  pos-emb-folded bias (Q part pre-scaled)
#define WS_W2A   84672    // [3*8*49][8] f16 : W2 i<8 (Q rows pre-scaled 1/7)
#define WS_W2B   103488   // [3*8*49][8] f16 : W2 i 8..16
#define WS_F1H   122304   // u32[16*196] fc1 weights as f16 pairs
#define WS_F1B   134848   // f32[16]
#define WS_F2W   134912   // f32[160]
#define WS_F2B   135552   // f32[10]

__device__ __forceinline__ u32 packh2(float a, float b) {
  h2 h; h.x = (_Float16)a; h.y = (_Float16)b;
  return __builtin_bit_cast(u32, h);
}
__device__ __forceinline__ float dot2u(u32 a, u32 b, float c) {
#if __has_builtin(__builtin_amdgcn_fdot2)
  return __builtin_amdgcn_fdot2(__builtin_bit_cast(h2, a), __builtin_bit_cast(h2, b), c, false);
#else
  h2 ha = __builtin_bit_cast(h2, a), hb = __builtin_bit_cast(h2, b);
  return c + (float)ha.x * (float)hb.x + (float)ha.y * (float)hb.y;
#endif
}
// 16-dim dot: 8 h2 input pairs vs two 16B weight planes
__device__ __forceinline__ float dot16(const u32* t, uint4 a, uint4 b, float c) {
  c = dot2u(t[0], a.x, c); c = dot2u(t[1], a.y, c);
  c = dot2u(t[2], a.z, c); c = dot2u(t[3], a.w, c);
  c = dot2u(t[4], b.x, c); c = dot2u(t[5], b.y, c);
  c = dot2u(t[6], b.z, c); c = dot2u(t[7], b.w, c);
  return c;
}

// ---------------- prep ----------------
extern "C" __global__ void vit_prep(
    const float* __restrict__ pe,
    const float* __restrict__ wq1, const float* __restrict__ wk1, const float* __restrict__ wv1,
    const float* __restrict__ wq2, const float* __restrict__ wk2, const float* __restrict__ wv2,
    const float* __restrict__ fw1, const float* __restrict__ fb1,
    const float* __restrict__ fw2, const float* __restrict__ fb2,
    char* __restrict__ ws)
{
  const int t = blockIdx.x * 256 + threadIdx.x;
  _Float16* w1aH = (_Float16*)(ws + WS_W1A);
  _Float16* w1bH = (_Float16*)(ws + WS_W1B);
  float*    cq   = (float*)(ws + WS_CQ);
  _Float16* w2aH = (_Float16*)(ws + WS_W2A);
  _Float16* w2bH = (_Float16*)(ws + WS_W2B);
  u32* f1h = (u32*)(ws + WS_F1H);
  float* o1b = (float*)(ws + WS_F1B);
  float* o2w = (float*)(ws + WS_F2W);
  float* o2b = (float*)(ws + WS_F2B);

  if (t < 2352) {                       // W1 rows: t = (p*16+o)*49+s
    int p = t / 784, rem = t % 784;
    int o = rem / 49, s = rem % 49;
    const float* W = (p == 0 ? wq1 : (p == 1 ? wk1 : wv1)) + s*512 + o*32;
    float sc = (p == 0) ? (1.0f/7.0f) : 1.0f;   // fold attn scale into Q
    #pragma unroll
    for (int i = 0; i < 8; ++i) w1aH[t*8 + i] = (_Float16)(W[i] * sc);
    #pragma unroll
    for (int i = 0; i < 8; ++i) w1bH[t*8 + i] = (_Float16)(W[8 + i] * sc);
    float acc = 0.f;
    #pragma unroll
    for (int i = 0; i < 16; ++i) acc += pe[s*16 + i] * W[16 + i];
    cq[t] = acc * sc;
  } else if (t < 3528) {                // W2 rows: u = (p*8+o)*49+s
    int u = t - 2352;
    int p = u / 392, rem = u % 392;
    int o = rem / 49, s = rem % 49;
    const float* W = (p == 0 ? wq2 : (p == 1 ? wk2 : wv2)) + s*128 + o*16;
    float sc = (p == 0) ? (1.0f/7.0f) : 1.0f;
    #pragma unroll
    for (int i = 0; i < 8; ++i) w2aH[u*8 + i] = (_Float16)(W[i] * sc);
    #pragma unroll
    for (int i = 0; i < 8; ++i) w2bH[u*8 + i] = (_Float16)(W[8 + i] * sc);
  } else if (t < 6664) {                // fc1 f16 pairs: u = h*196 + jc
    int u = t - 3528;
    int h = u / 196, jc = u % 196;
    f1h[u] = packh2(fw1[h*392 + 2*jc], fw1[h*392 + 2*jc + 1]);
  } else if (t < 6680) {
    int u = t - 6664; o1b[u] = fb1[u];
  } else if (t < 6840) {
    int u = t - 6680; o2w[u] = fw2[u];
  } else if (t < 6850) {
    int u = t - 6840; o2b[u] = fb2[u];
  }
}

// ---------------- main fused kernel ----------------
// block=256 (4 waves), grid=256, 4 iters, NS=4 samples per wave per iter.
// LDS: [0,84672) = W1 planes + CQ. Then per wave 16384 B = 4 sample regions of 4096:
//   su+0    : Q1 f16 rows [16][56]   (1792 B)  -> later Q2 [8][56] (896) / K2 @+896 / t3h (784)
//   su+1792 : K1 f16 rows [16][56]   (1792 B)
//   su+3584 : S1h u32[16][8] (512)   -> later S2h u32[8][4] (128); hb f32[16] @+192; lg f32[10] @+256
extern "C" __global__ void __launch_bounds__(256, 1)
vit_main(const float* __restrict__ x, const char* __restrict__ ws, float* __restrict__ out)
{
  __shared__ uint4 smem4[150208 / 16];
  char* smem = (char*)smem4;
  const u32 tid  = threadIdx.x;
  const u32 lane = tid & 63u;
  const u32 wv   = tid >> 6;

  { // stage W1 + CQ into LDS once
    const uint4* src = (const uint4*)ws;
    uint4* dst = (uint4*)smem;
    for (u32 i = tid; i < (84672u / 16u); i += 256u) dst[i] = src[i];
  }
  __syncthreads();

  const uint4* w1a = (const uint4*)(smem + WS_W1A);
  const uint4* w1b = (const uint4*)(smem + WS_W1B);
  const float* cqb = (const float*)(smem + WS_CQ);
  const uint4* g2a = (const uint4*)(ws + WS_W2A);
  const uint4* g2b = (const uint4*)(ws + WS_W2B);
  const uint4* f1hg = (const uint4*)(ws + WS_F1H);
  const float* f1bg = (const float*)(ws + WS_F1B);
  const float* f2wg = (const float*)(ws + WS_F2W);
  const float* f2bg = (const float*)(ws + WS_F2B);

  char* pw = smem + 84672 + wv * 16384;
  const u32 s = lane;          // patch index role in s-phases
  const u32 pr = s / 7u, pc = s - pr * 7u;

  for (u32 iter = 0; iter < 4u; ++iter) {
    const u32 bbase = blockIdx.x * 64u + iter * 16u + wv * 4u;

    u32 p2h[4][8];   // 4 samples x 8 h2 patch pairs
    u32 v1h[4][8];   // V1 e-pairs
    u32 th4[4][8];   // tok2 pairs
    u32 v2h[4][4];   // V2 e-pairs

    // ---- P1: patchify directly to registers (no LDS) ----
    if (s < 49u) {
      #pragma unroll
      for (int u = 0; u < 4; ++u) {
        const float* xb = x + (size_t)(bbase + u) * 2352u;
        #pragma unroll
        for (int r = 0; r < 4; ++r) {
          const float* rp = xb + (4u*pr + r) * 28u + 4u*pc;
          float4 rr = *(const float4*)rp;
          float4 gg = *(const float4*)(rp + 784);
          float4 bb = *(const float4*)(rp + 1568);
          float g0 = 0.299f*rr.x + 0.587f*gg.x + 0.114f*bb.x;
          float g1 = 0.299f*rr.y + 0.587f*gg.y + 0.114f*bb.y;
          float g2 = 0.299f*rr.z + 0.587f*gg.z + 0.114f*bb.z;
          float g3 = 0.299f*rr.w + 0.587f*gg.w + 0.114f*bb.w;
          p2h[u][r*2]   = packh2(g0, g1);
          p2h[u][r*2+1] = packh2(g2, g3);
        }
      }
    }

    // ---- P2: proj1, weights amortized over 4 samples; Q/K -> f16 [d][56] rows ----
    if (s < 49u) {
      #pragma unroll
      for (int op = 0; op < 8; ++op) {
        const int o = 2*op;
        const int r0 = o*49 + (int)s;
        uint4 aq0 = w1a[r0],      bq0 = w1b[r0];
        uint4 aq1 = w1a[r0+49],   bq1 = w1b[r0+49];
        uint4 ak0 = w1a[r0+784],  bk0 = w1b[r0+784];
        uint4 ak1 = w1a[r0+833],  bk1 = w1b[r0+833];
        uint4 av0 = w1a[r0+1568], bv0 = w1b[r0+1568];
        uint4 av1 = w1a[r0+1617], bv1 = w1b[r0+1617];
        float cq0 = cqb[r0],     cq1 = cqb[r0+49];
        float ck0 = cqb[r0+784], ck1 = cqb[r0+833];
        float cv0 = cqb[r0+1568], cv1 = cqb[r0+1617];
        #pragma unroll
        for (int u = 0; u < 4; ++u) {
          char* su = pw + u*4096;
          float q0 = dot16(p2h[u], aq0, bq0, cq0);
          float q1 = dot16(p2h[u], aq1, bq1, cq1);
          float k0 = dot16(p2h[u], ak0, bk0, ck0);
          float k1 = dot16(p2h[u], ak1, bk1, ck1);
          float v0 = dot16(p2h[u], av0, bv0, cv0);
          float v1 = dot16(p2h[u], av1, bv1, cv1);
          _Float16* qrow = (_Float16*)su;
          _Float16* krow = (_Float16*)(su + 1792);
          qrow[o*56 + s]     = (_Float16)q0;
          qrow[(o+1)*56 + s] = (_Float16)q1;
          krow[o*56 + s]     = (_Float16)k0;
          krow[(o+1)*56 + s] = (_Float16)k1;
          v1h[u][op] = packh2(v0, v1);
        }
      }
    }
    __syncthreads();

    // ---- P3: S1[d,e] via dot2 over s-pairs; lane=(d2,e2) 8x8 ----
    {
      const u32 d2 = lane >> 3, e2 = lane & 7u;
      #pragma unroll
      for (int u = 0; u < 4; ++u) {
        char* su = pw + u*4096;
        const u32* qw = (const u32*)su;
        const u32* kw = (const u32*)(su + 1792);
        const u32* qA = qw + (2u*d2) * 28u;
        const u32* qB = qA + 28u;
        const u32* kA = kw + (2u*e2) * 28u;
        const u32* kB = kA + 28u;
        float a00 = 0.f, a01 = 0.f, a10 = 0.f, a11 = 0.f;
        #pragma unroll
        for (int t7 = 0; t7 < 6; ++t7) {
          uint4 qa = *(const uint4*)(qA + 4*t7);
          uint4 qb = *(const uint4*)(qB + 4*t7);
          uint4 ka = *(const uint4*)(kA + 4*t7);
          uint4 kb = *(const uint4*)(kB + 4*t7);
          a00 = dot2u(qa.x, ka.x, a00); a00 = dot2u(qa.y, ka.y, a00);
          a00 = dot2u(qa.z, ka.z, a00); a00 = dot2u(qa.w, ka.w, a00);
          a01 = dot2u(qa.x, kb.x, a01); a01 = dot2u(qa.y, kb.y, a01);
          a01 = dot2u(qa.z, kb.z, a01); a01 = dot2u(qa.w, kb.w, a01);
          a10 = dot2u(qb.x, ka.x, a10); a10 = dot2u(qb.y, ka.y, a10);
          a10 = dot2u(qb.z, ka.z, a10); a10 = dot2u(qb.w, ka.w, a10);
          a11 = dot2u(qb.x, kb.x, a11); a11 = dot2u(qb.y, kb.y, a11);
          a11 = dot2u(qb.z, kb.z, a11); a11 = dot2u(qb.w, kb.w, a11);
        }
        { // tail s = 48 (exact-width reads; pads are garbage)
          float q0t = (float)((const _Float16*)qA)[48];
          float q1t = (float)((const _Float16*)qB)[48];
          float k0t = (float)((const _Float16*)kA)[48];
          float k1t = (float)((const _Float16*)kB)[48];
          a00 = fmaf(q0t, k0t, a00); a01 = fmaf(q0t, k1t, a01);
          a10 = fmaf(q1t, k0t, a10); a11 = fmaf(q1t, k1t, a11);
        }
        u32* s1 = (u32*)(su + 3584);
        s1[(2u*d2)*8u + e2]   = packh2(a00, a01);
        s1[(2u*d2+1)*8u + e2] = packh2(a10, a11);
      }
    }
    __syncthreads();

    // ---- P4a: out1 + softmax16 -> th4 (tok2 h2 pairs) ----
    if (s < 49u) {
      #pragma unroll
      for (int u = 0; u < 4; ++u) {
        char* su = pw + u*4096;
        const u32* s1 = (const u32*)(su + 3584);
        float od[16];
        #pragma unroll
        for (int d = 0; d < 16; ++d) {
          uint4 sa = *(const uint4*)&s1[d*8];
          uint4 sb = *(const uint4*)&s1[d*8 + 4];
          float acc = dot2u(sa.x, v1h[u][0], 0.f);
          acc = dot2u(sa.y, v1h[u][1], acc);
          acc = dot2u(sa.z, v1h[u][2], acc);
          acc = dot2u(sa.w, v1h[u][3], acc);
          acc = dot2u(sb.x, v1h[u][4], acc);
          acc = dot2u(sb.y, v1h[u][5], acc);
          acc = dot2u(sb.z, v1h[u][6], acc);
          acc = dot2u(sb.w, v1h[u][7], acc);
          od[d] = acc;
        }
        float m = od[0];
        #pragma unroll
        for (int d = 1; d < 16; ++d) m = fmaxf(m, od[d]);
        float sum = 0.f;
        #pragma unroll
        for (int d = 0; d < 16; ++d) { od[d] = __expf(od[d] - m); sum += od[d]; }
        float rs = 1.0f / sum;
        #pragma unroll
        for (int j = 0; j < 8; ++j) th4[u][j] = packh2(od[2*j]*rs, od[2*j+1]*rs);
      }
    }

    // ---- P4b: proj2 (W2 from global/L1), amortized over 4 samples ----
    if (s < 49u) {
      #pragma unroll
      for (int op = 0; op < 4; ++op) {
        const int o = 2*op;
        const int r0 = o*49 + (int)s;
        uint4 aq0 = g2a[r0],     bq0 = g2b[r0];
        uint4 aq1 = g2a[r0+49],  bq1 = g2b[r0+49];
        uint4 ak0 = g2a[r0+392], bk0 = g2b[r0+392];
        uint4 ak1 = g2a[r0+441], bk1 = g2b[r0+441];
        uint4 av0 = g2a[r0+784], bv0 = g2b[r0+784];
        uint4 av1 = g2a[r0+833], bv1 = g2b[r0+833];
        #pragma unroll
        for (int u = 0; u < 4; ++u) {
          char* su = pw + u*4096;
          float q0 = dot16(th4[u], aq0, bq0, 0.f);
          float q1 = dot16(th4[u], aq1, bq1, 0.f);
          float k0 = dot16(th4[u], ak0, bk0, 0.f);
          float k1 = dot16(th4[u], ak1, bk1, 0.f);
          float v0 = dot16(th4[u], av0, bv0, 0.f);
          float v1 = dot16(th4[u], av1, bv1, 0.f);
          _Float16* qrow = (_Float16*)su;
          _Float16* krow = (_Float16*)(su + 896);
          qrow[o*56 + s]     = (_Float16)q0;
          qrow[(o+1)*56 + s] = (_Float16)q1;
          krow[o*56 + s]     = (_Float16)k0;
          krow[(o+1)*56 + s] = (_Float16)k1;
          v2h[u][op] = packh2(v0, v1);
        }
      }
    }
    __syncthreads();

    // ---- P5: S2[d,e] 8x8, all 64 lanes: (u, d2, e2) ----
    {
      const u32 uu = lane >> 4, d2 = (lane >> 2) & 3u, e2 = lane & 3u;
      char* su = pw + uu*4096;
      const u32* qw = (const u32*)su;
      const u32* kw = (const u32*)(su + 896);
      const u32* qA = qw + (2u*d2) * 28u;
      const u32* qB = qA + 28u;
      const u32* kA = kw + (2u*e2) * 28u;
      const u32* kB = kA + 28u;
      float a00 = 0.f, a01 = 0.f, a10 = 0.f, a11 = 0.f;
      #pragma unroll
      for (int t7 = 0; t7 < 6; ++t7) {
        uint4 qa = *(const uint4*)(qA + 4*t7);
        uint4 qb = *(const uint4*)(qB + 4*t7);
        uint4 ka = *(const uint4*)(kA + 4*t7);
        uint4 kb = *(const uint4*)(kB + 4*t7);
        a00 = dot2u(qa.x, ka.x, a00); a00 = dot2u(qa.y, ka.y, a00);
        a00 = dot2u(qa.z, ka.z, a00); a00 = dot2u(qa.w, ka.w, a00);
        a01 = dot2u(qa.x, kb.x, a01); a01 = dot2u(qa.y, kb.y, a01);
        a01 = dot2u(qa.z, kb.z, a01); a01 = dot2u(qa.w, kb.w, a01);
        a10 = dot2u(qb.x, ka.x, a10); a10 = dot2u(qb.y, ka.y, a10);
        a10 = dot2u(qb.z, ka.z, a10); a10 = dot2u(qb.w, ka.w, a10);
        a11 = dot2u(qb.x, kb.x, a11); a11 = dot2u(qb.y, kb.y, a11);
        a11 = dot2u(qb.z, kb.z, a11); a11 = dot2u(qb.w, kb.w, a11);
      }
      {
        float q0t = (float)((const _Float16*)qA)[48];
        float q1t = (float)((const _Float16*)qB)[48];
        float k0t = (float)((const _Float16*)kA)[48];
        float k1t = (float)((const _Float16*)kB)[48];
        a00 = fmaf(q0t, k0t, a00); a01 = fmaf(q0t, k1t, a01);
        a10 = fmaf(q1t, k0t, a10); a11 = fmaf(q1t, k1t, a11);
      }
      u32* s2 = (u32*)(su + 3584);
      s2[(2u*d2)*4u + e2]   = packh2(a00, a01);
      s2[(2u*d2+1)*4u + e2] = packh2(a10, a11);
    }
    __syncthreads();

    // ---- P6: out2 + softmax8 -> t3h (f16 pairs) ----
    if (s < 49u) {
      #pragma unroll
      for (int u = 0; u < 4; ++u) {
        char* su = pw + u*4096;
        const u32* s2 = (const u32*)(su + 3584);
        float od[8];
        #pragma unroll
        for (int d = 0; d < 8; ++d) {
          uint4 sr = *(const uint4*)&s2[d*4];
          float acc = dot2u(sr.x, v2h[u][0], 0.f);
          acc = dot2u(sr.y, v2h[u][1], acc);
          acc = dot2u(sr.z, v2h[u][2], acc);
          acc = dot2u(sr.w, v2h[u][3], acc);
          od[d] = acc;
        }
        float m = od[0];
        #pragma unroll
        for (int d = 1; d < 8; ++d) m = fmaxf(m, od[d]);
        float sum = 0.f;
        #pragma unroll
        for (int d = 0; d < 8; ++d) { od[d] = __expf(od[d] - m); sum += od[d]; }
        float rs = 1.0f / sum;
        uint4 tw;
        tw.x = packh2(od[0]*rs, od[1]*rs);
        tw.y = packh2(od[2]*rs, od[3]*rs);
        tw.z = packh2(od[4]*rs, od[5]*rs);
        tw.w = packh2(od[6]*rs, od[7]*rs);
        *(uint4*)((u32*)su + s*4u) = tw;
      }
    }
    __syncthreads();

    // ---- P7: fc1 + relu, lane = (u, h) ----
    {
      const u32 uu = lane >> 4, h = lane & 15u;
      char* su = pw + uu*4096;
      const u32* t3 = (const u32*)su;
      float acc = f1bg[h];
      #pragma unroll 7
      for (int j = 0; j < 49; ++j) {
        uint4 tj = *(const uint4*)&t3[j*4];
        uint4 wj = f1hg[h*49u + (u32)j];
        acc = dot2u(tj.x, wj.x, acc);
        acc = dot2u(tj.y, wj.y, acc);
        acc = dot2u(tj.z, wj.z, acc);
        acc = dot2u(tj.w, wj.w, acc);
      }
      float* hb = (float*)(su + 3584 + 192);
      hb[h] = fmaxf(acc, 0.f);
    }
    __syncthreads();

    // ---- fc2, lane = (u, c<10) ----
    {
      const u32 uu = lane >> 4, c = lane & 15u;
      char* su = pw + uu*4096;
      if (c < 10u) {
        const float* hb = (const float*)(su + 3584 + 192);
        float4 h0 = *(const float4*)&hb[0];
        float4 h1 = *(const float4*)&hb[4];
        float4 h2v = *(const float4*)&hb[8];
        float4 h3 = *(const float4*)&hb[12];
        const float* wr = f2wg + c*16u;
        float4 w0 = *(const float4*)&wr[0];
        float4 w1 = *(const float4*)&wr[4];
        float4 w2 = *(const float4*)&wr[8];
        float4 w3 = *(const float4*)&wr[12];
        float acc = f2bg[c];
        acc = fmaf(h0.x, w0.x, acc); acc = fmaf(h0.y, w0.y, acc);
        acc = fmaf(h0.z, w0.z, acc); acc = fmaf(h0.w, w0.w, acc);
        acc = fmaf(h1.x, w1.x, acc); acc = fmaf(h1.y, w1.y, acc);
        acc = fmaf(h1.z, w1.z, acc); acc = fmaf(h1.w, w1.w, acc);
        acc = fmaf(h2v.x, w2.x, acc); acc = fmaf(h2v.y, w2.y, acc);
        acc = fmaf(h2v.z, w2.z, acc); acc = fmaf(h2v.w, w2.w, acc);
        acc = fmaf(h3.x, w3.x, acc); acc = fmaf(h3.y, w3.y, acc);
        acc = fmaf(h3.z, w3.z, acc); acc = fmaf(h3.w, w3.w, acc);
        float* lg = (float*)(su + 3584 + 256);
        lg[c] = acc;
      }
    }
    __syncthreads();

    // ---- softmax10 + store ----
    {
      const u32 uu = lane >> 4, c = lane & 15u;
      char* su = pw + uu*4096;
      if (c < 10u) {
        const float* lg = (const float*)(su + 3584 + 256);
        float mx = lg[0];
        #pragma unroll
        for (int i = 1; i < 10; ++i) mx = fmaxf(mx, lg[i]);
        float sum = 0.f;
        #pragma unroll
        for (int i = 0; i < 10; ++i) sum += __expf(lg[i] - mx);
        out[(size_t)(bbase + uu) * 10u + c] = __expf(lg[c] - mx) / sum;
      }
    }
    __syncthreads();   // protect per-wave LDS reuse next iteration
  }
}

extern "C" void kernel_launch(void* const* d_in, const int* in_sizes, int n_in,
                              void* d_out, int out_size, void* d_ws, size_t ws_size,
                              hipStream_t stream)
{
  const float* x   = (const float*)d_in[0];
  const float* pe  = (const float*)d_in[1];
  const float* wq1 = (const float*)d_in[2];
  const float* wk1 = (const float*)d_in[3];
  const float* wv1 = (const float*)d_in[4];
  const float* wq2 = (const float*)d_in[5];
  const float* wk2 = (const float*)d_in[6];
  const float* wv2 = (const float*)d_in[7];
  const float* f1w = (const float*)d_in[8];
  const float* f1b = (const float*)d_in[9];
  const float* f2w = (const float*)d_in[10];
  const float* f2b = (const float*)d_in[11];
  char* ws = (char*)d_ws;
  float* out = (float*)d_out;

  hipLaunchKernelGGL(vit_prep, dim3(27), dim3(256), 0, stream,
                     pe, wq1, wk1, wv1, wq2, wk2, wv2, f1w, f1b, f2w, f2b, ws);
  hipLaunchKernelGGL(vit_main, dim3(256), dim3(256), 0, stream, x, ws, out);
}